// Round 1
// baseline (3012.697 us; speedup 1.0000x reference)
//
#include <hip/hip_runtime.h>
#include <hip/hip_bf16.h>

// Problem constants (from reference)
#define HDIM 2048
#define IDIM 1024
#define NEXP 16
#define TTOK 4096   // B*S tokens
#define KTOP 2

typedef __attribute__((ext_vector_type(4))) float f32x4;
typedef __attribute__((ext_vector_type(8))) short bf16x8;     // MFMA A/B frag (8 bf16)
typedef __attribute__((ext_vector_type(8))) unsigned short u16x8;

__device__ __forceinline__ unsigned short f2b(float f) {
  __hip_bfloat16 h = __float2bfloat16(f);
  return *reinterpret_cast<unsigned short*>(&h);
}

// ---------------------------------------------------------------- zero
__global__ __launch_bounds__(256) void zero_out_kernel(float* __restrict__ out,
                                                       int* __restrict__ counts) {
  const int n4 = TTOK * HDIM / 4;
  f32x4 z = {0.f, 0.f, 0.f, 0.f};
  for (int i = blockIdx.x * 256 + threadIdx.x; i < n4; i += gridDim.x * 256)
    reinterpret_cast<f32x4*>(out)[i] = z;
  if (blockIdx.x == 0 && threadIdx.x < NEXP) counts[threadIdx.x] = 0;
}

// ---------------------------------------------------------------- x -> bf16
__global__ __launch_bounds__(256) void convert_x_kernel(const float* __restrict__ x,
                                                        unsigned short* __restrict__ xb) {
  const int i = blockIdx.x * 256 + threadIdx.x;  // one thread per 8 elements
  const f32x4* src = reinterpret_cast<const f32x4*>(x) + (size_t)i * 2;
  f32x4 v0 = src[0], v1 = src[1];
  u16x8 o;
  o[0] = f2b(v0[0]); o[1] = f2b(v0[1]); o[2] = f2b(v0[2]); o[3] = f2b(v0[3]);
  o[4] = f2b(v1[0]); o[5] = f2b(v1[1]); o[6] = f2b(v1[2]); o[7] = f2b(v1[3]);
  reinterpret_cast<u16x8*>(xb)[i] = o;
}

// ---------------------------------------------------------------- gating
// one wave per token: 16 dot products over H, butterfly reduce, top-2,
// normalized weights = softmax ratio of top-2 logits (softmax denom cancels).
__global__ __launch_bounds__(256) void gating_kernel(const float* __restrict__ x,
                                                     const float* __restrict__ gw,
                                                     float* __restrict__ tw,
                                                     int* __restrict__ counts,
                                                     int* __restrict__ list) {
  const int wv = threadIdx.x >> 6;
  const int lane = threadIdx.x & 63;
  const int t = blockIdx.x * 4 + wv;

  float acc[NEXP];
#pragma unroll
  for (int e = 0; e < NEXP; ++e) acc[e] = 0.f;

  const float* xr = x + (size_t)t * HDIM;
  for (int j = 0; j < HDIM / 64; ++j) {
    float xv = xr[j * 64 + lane];
#pragma unroll
    for (int e = 0; e < NEXP; ++e)
      acc[e] = fmaf(xv, gw[e * HDIM + j * 64 + lane], acc[e]);
  }
#pragma unroll
  for (int e = 0; e < NEXP; ++e) {
#pragma unroll
    for (int off = 32; off; off >>= 1) acc[e] += __shfl_xor(acc[e], off);
  }
  // top-2 (ties -> lowest index, matching lax.top_k)
  int i0 = 0; float s0 = acc[0];
#pragma unroll
  for (int e = 1; e < NEXP; ++e) { if (acc[e] > s0) { s0 = acc[e]; i0 = e; } }
  int i1 = -1; float s1 = -1e30f;
#pragma unroll
  for (int e = 0; e < NEXP; ++e) { if (e != i0 && acc[e] > s1) { s1 = acc[e]; i1 = e; } }

  if (lane == 0) {
    float r = __expf(s1 - s0);          // <= 1
    float w0 = 1.f / (1.f + r);
    float w1 = r / (1.f + r);
    tw[t * 2 + 0] = w0;
    tw[t * 2 + 1] = w1;
    int p0 = atomicAdd(&counts[i0], 1); list[i0 * TTOK + p0] = t * 2 + 0;
    int p1 = atomicAdd(&counts[i1], 1); list[i1 * TTOK + p1] = t * 2 + 1;
  }
}

// ---------------------------------------------------------------- GEMMs
#define BM 64
#define BN 64
#define BK 64

// byte offset in a [64 rows][64 bf16] LDS tile, XOR-swizzled (16B granule)
__device__ __forceinline__ int swz(int row, int kb) {
  return (row * 128 + kb) ^ ((row & 7) << 4);
}

// GEMM1: act[slot, :] = silu(x@wg) * (x@wu) * weight   for each routed slot
__global__ __launch_bounds__(256) void gemm1_kernel(
    const unsigned short* __restrict__ xb, const float* __restrict__ wg,
    const float* __restrict__ wu, const int* __restrict__ counts,
    const int* __restrict__ list, const float* __restrict__ tw,
    unsigned short* __restrict__ act) {
  const int e = blockIdx.z;
  const int cnt = counts[e];
  const int m0 = blockIdx.x * BM;
  if (m0 >= cnt) return;
  const int n0 = blockIdx.y * BN;

  __shared__ __align__(16) char As[BM * BK * 2];
  __shared__ __align__(16) char Bgs[BN * BK * 2];
  __shared__ __align__(16) char Bus[BN * BK * 2];
  __shared__ int slot_s[BM];
  __shared__ float ws_s[BM];

  const int tid = threadIdx.x;
  if (tid < BM) {
    int mr = m0 + tid;
    int mrc = mr < cnt ? mr : cnt - 1;
    int slot = list[e * TTOK + mrc];
    slot_s[tid] = slot;
    ws_s[tid] = tw[slot];
  }
  __syncthreads();

  const int s_row = tid >> 3;   // 0..31 (A-row / B-col), second at +32
  const int s_koct = tid & 7;   // k-octet 0..7

  const size_t a_off0 = (size_t)(slot_s[s_row] >> 1) * HDIM;
  const size_t a_off1 = (size_t)(slot_s[s_row + 32] >> 1) * HDIM;
  const float* wgp = wg + (size_t)e * HDIM * IDIM + n0 + s_row;
  const float* wup = wu + (size_t)e * HDIM * IDIM + n0 + s_row;

  f32x4 accg[2][2], accu[2][2];
#pragma unroll
  for (int mi = 0; mi < 2; ++mi)
#pragma unroll
    for (int ni = 0; ni < 2; ++ni) {
      accg[mi][ni] = (f32x4){0.f, 0.f, 0.f, 0.f};
      accu[mi][ni] = (f32x4){0.f, 0.f, 0.f, 0.f};
    }

  const int lane = tid & 63;
  const int wv = tid >> 6;
  const int wm = (wv >> 1) * 32;
  const int wn = (wv & 1) * 32;
  const int fr = lane & 15;
  const int fk = lane >> 4;

  for (int k0 = 0; k0 < HDIM; k0 += BK) {
    // global loads (issued before barrier -> overlap previous MFMA)
    u16x8 av0 = *reinterpret_cast<const u16x8*>(xb + a_off0 + k0 + s_koct * 8);
    u16x8 av1 = *reinterpret_cast<const u16x8*>(xb + a_off1 + k0 + s_koct * 8);
    const float* pg = wgp + (size_t)(k0 + s_koct * 8) * IDIM;
    const float* pu = wup + (size_t)(k0 + s_koct * 8) * IDIM;
    float g0[8], g1[8], u0[8], u1[8];
#pragma unroll
    for (int j = 0; j < 8; ++j) {
      g0[j] = pg[j * IDIM];
      g1[j] = pg[j * IDIM + 32];
      u0[j] = pu[j * IDIM];
      u1[j] = pu[j * IDIM + 32];
    }
    __syncthreads();  // previous iteration's MFMA reads complete
    *reinterpret_cast<u16x8*>(As + swz(s_row, s_koct * 16)) = av0;
    *reinterpret_cast<u16x8*>(As + swz(s_row + 32, s_koct * 16)) = av1;
    u16x8 vg0, vg1, vu0, vu1;
#pragma unroll
    for (int j = 0; j < 8; ++j) {
      vg0[j] = f2b(g0[j]); vg1[j] = f2b(g1[j]);
      vu0[j] = f2b(u0[j]); vu1[j] = f2b(u1[j]);
    }
    *reinterpret_cast<u16x8*>(Bgs + swz(s_row, s_koct * 16)) = vg0;
    *reinterpret_cast<u16x8*>(Bgs + swz(s_row + 32, s_koct * 16)) = vg1;
    *reinterpret_cast<u16x8*>(Bus + swz(s_row, s_koct * 16)) = vu0;
    *reinterpret_cast<u16x8*>(Bus + swz(s_row + 32, s_koct * 16)) = vu1;
    __syncthreads();

#pragma unroll
    for (int ks = 0; ks < 2; ++ks) {
      const int kb = ks * 64 + fk * 16;
      bf16x8 a0 = *reinterpret_cast<bf16x8*>(As + swz(wm + fr, kb));
      bf16x8 a1 = *reinterpret_cast<bf16x8*>(As + swz(wm + 16 + fr, kb));
      bf16x8 bg0 = *reinterpret_cast<bf16x8*>(Bgs + swz(wn + fr, kb));
      bf16x8 bg1 = *reinterpret_cast<bf16x8*>(Bgs + swz(wn + 16 + fr, kb));
      bf16x8 bu0 = *reinterpret_cast<bf16x8*>(Bus + swz(wn + fr, kb));
      bf16x8 bu1 = *reinterpret_cast<bf16x8*>(Bus + swz(wn + 16 + fr, kb));
      accg[0][0] = __builtin_amdgcn_mfma_f32_16x16x32_bf16(a0, bg0, accg[0][0], 0, 0, 0);
      accg[0][1] = __builtin_amdgcn_mfma_f32_16x16x32_bf16(a0, bg1, accg[0][1], 0, 0, 0);
      accg[1][0] = __builtin_amdgcn_mfma_f32_16x16x32_bf16(a1, bg0, accg[1][0], 0, 0, 0);
      accg[1][1] = __builtin_amdgcn_mfma_f32_16x16x32_bf16(a1, bg1, accg[1][1], 0, 0, 0);
      accu[0][0] = __builtin_amdgcn_mfma_f32_16x16x32_bf16(a0, bu0, accu[0][0], 0, 0, 0);
      accu[0][1] = __builtin_amdgcn_mfma_f32_16x16x32_bf16(a0, bu1, accu[0][1], 0, 0, 0);
      accu[1][0] = __builtin_amdgcn_mfma_f32_16x16x32_bf16(a1, bu0, accu[1][0], 0, 0, 0);
      accu[1][1] = __builtin_amdgcn_mfma_f32_16x16x32_bf16(a1, bu1, accu[1][1], 0, 0, 0);
    }
  }

  // epilogue: silu(g)*u*w -> bf16 act
#pragma unroll
  for (int mi = 0; mi < 2; ++mi)
#pragma unroll
    for (int ni = 0; ni < 2; ++ni)
#pragma unroll
      for (int r = 0; r < 4; ++r) {
        const int trow = wm + mi * 16 + fk * 4 + r;
        if (m0 + trow < cnt) {
          const int col = n0 + wn + ni * 16 + fr;
          const float g = accg[mi][ni][r];
          const float u = accu[mi][ni][r];
          const float a = (g / (1.f + __expf(-g))) * u * ws_s[trow];
          act[(size_t)slot_s[trow] * IDIM + col] = f2b(a);
        }
      }
}

// GEMM2: out[token, :] += act[slot, :] @ wd[e]
__global__ __launch_bounds__(256) void gemm2_kernel(
    const unsigned short* __restrict__ act, const float* __restrict__ wd,
    const int* __restrict__ counts, const int* __restrict__ list,
    float* __restrict__ out) {
  const int e = blockIdx.z;
  const int cnt = counts[e];
  const int m0 = blockIdx.x * BM;
  if (m0 >= cnt) return;
  const int n0 = blockIdx.y * BN;

  __shared__ __align__(16) char As[BM * BK * 2];
  __shared__ __align__(16) char Bs[BN * BK * 2];
  __shared__ int slot_s[BM];

  const int tid = threadIdx.x;
  if (tid < BM) {
    int mr = m0 + tid;
    int mrc = mr < cnt ? mr : cnt - 1;
    slot_s[tid] = list[e * TTOK + mrc];
  }
  __syncthreads();

  const int s_row = tid >> 3;
  const int s_koct = tid & 7;
  const size_t a_off0 = (size_t)slot_s[s_row] * IDIM;
  const size_t a_off1 = (size_t)slot_s[s_row + 32] * IDIM;
  const float* wdp = wd + (size_t)e * IDIM * HDIM + n0 + s_row;

  f32x4 acc[2][2];
#pragma unroll
  for (int mi = 0; mi < 2; ++mi)
#pragma unroll
    for (int ni = 0; ni < 2; ++ni) acc[mi][ni] = (f32x4){0.f, 0.f, 0.f, 0.f};

  const int lane = tid & 63;
  const int wv = tid >> 6;
  const int wm = (wv >> 1) * 32;
  const int wn = (wv & 1) * 32;
  const int fr = lane & 15;
  const int fk = lane >> 4;

  for (int k0 = 0; k0 < IDIM; k0 += BK) {
    u16x8 av0 = *reinterpret_cast<const u16x8*>(act + a_off0 + k0 + s_koct * 8);
    u16x8 av1 = *reinterpret_cast<const u16x8*>(act + a_off1 + k0 + s_koct * 8);
    const float* pb = wdp + (size_t)(k0 + s_koct * 8) * HDIM;
    float b0[8], b1[8];
#pragma unroll
    for (int j = 0; j < 8; ++j) {
      b0[j] = pb[j * HDIM];
      b1[j] = pb[j * HDIM + 32];
    }
    __syncthreads();
    *reinterpret_cast<u16x8*>(As + swz(s_row, s_koct * 16)) = av0;
    *reinterpret_cast<u16x8*>(As + swz(s_row + 32, s_koct * 16)) = av1;
    u16x8 vb0, vb1;
#pragma unroll
    for (int j = 0; j < 8; ++j) { vb0[j] = f2b(b0[j]); vb1[j] = f2b(b1[j]); }
    *reinterpret_cast<u16x8*>(Bs + swz(s_row, s_koct * 16)) = vb0;
    *reinterpret_cast<u16x8*>(Bs + swz(s_row + 32, s_koct * 16)) = vb1;
    __syncthreads();

#pragma unroll
    for (int ks = 0; ks < 2; ++ks) {
      const int kb = ks * 64 + fk * 16;
      bf16x8 a0 = *reinterpret_cast<bf16x8*>(As + swz(wm + fr, kb));
      bf16x8 a1 = *reinterpret_cast<bf16x8*>(As + swz(wm + 16 + fr, kb));
      bf16x8 b0 = *reinterpret_cast<bf16x8*>(Bs + swz(wn + fr, kb));
      bf16x8 b1 = *reinterpret_cast<bf16x8*>(Bs + swz(wn + 16 + fr, kb));
      acc[0][0] = __builtin_amdgcn_mfma_f32_16x16x32_bf16(a0, b0, acc[0][0], 0, 0, 0);
      acc[0][1] = __builtin_amdgcn_mfma_f32_16x16x32_bf16(a0, b1, acc[0][1], 0, 0, 0);
      acc[1][0] = __builtin_amdgcn_mfma_f32_16x16x32_bf16(a1, b0, acc[1][0], 0, 0, 0);
      acc[1][1] = __builtin_amdgcn_mfma_f32_16x16x32_bf16(a1, b1, acc[1][1], 0, 0, 0);
    }
  }

#pragma unroll
  for (int mi = 0; mi < 2; ++mi)
#pragma unroll
    for (int ni = 0; ni < 2; ++ni)
#pragma unroll
      for (int r = 0; r < 4; ++r) {
        const int trow = wm + mi * 16 + fk * 4 + r;
        if (m0 + trow < cnt) {
          const int t = slot_s[trow] >> 1;
          const int col = n0 + wn + ni * 16 + fr;
          atomicAdd(&out[(size_t)t * HDIM + col], acc[mi][ni][r]);
        }
      }
}

// ---------------------------------------------------------------- launch
extern "C" void kernel_launch(void* const* d_in, const int* in_sizes, int n_in,
                              void* d_out, int out_size, void* d_ws, size_t ws_size,
                              hipStream_t stream) {
  const float* x = (const float*)d_in[0];
  const float* gate_w = (const float*)d_in[1];
  const float* wg = (const float*)d_in[2];
  const float* wu = (const float*)d_in[3];
  const float* wd = (const float*)d_in[4];
  float* out = (float*)d_out;

  // workspace layout (~33.9 MB)
  char* w = (char*)d_ws;
  size_t off = 0;
  unsigned short* xb = (unsigned short*)(w + off); off += (size_t)TTOK * HDIM * 2;
  unsigned short* act = (unsigned short*)(w + off); off += (size_t)TTOK * KTOP * IDIM * 2;
  float* tw = (float*)(w + off); off += (size_t)TTOK * KTOP * 4;
  int* counts = (int*)(w + off); off += 256;
  int* list = (int*)(w + off); off += (size_t)NEXP * TTOK * 4;

  zero_out_kernel<<<2048, 256, 0, stream>>>(out, counts);
  convert_x_kernel<<<TTOK * HDIM / 8 / 256, 256, 0, stream>>>(x, xb);
  gating_kernel<<<TTOK / 4, 256, 0, stream>>>(x, gate_w, tw, counts, list);
  gemm1_kernel<<<dim3(TTOK / BM, IDIM / BN, NEXP), 256, 0, stream>>>(
      xb, wg, wu, counts, list, tw, act);
  gemm2_kernel<<<dim3(TTOK / BM, HDIM / BN, NEXP), 256, 0, stream>>>(
      act, wd, counts, list, out);
}

// Round 3
// 1226.734 us; speedup vs baseline: 2.4559x; 2.4559x over previous
//
#include <hip/hip_runtime.h>
#include <hip/hip_bf16.h>

#define HDIM 2048
#define IDIM 1024
#define NEXP 16
#define TTOK 4096   // B*S tokens
#define KTOP 2
#define BM 64
#define BN 64
#define BK 64

typedef __attribute__((ext_vector_type(4))) float f32x4;
typedef __attribute__((ext_vector_type(8))) short bf16x8;
typedef __attribute__((ext_vector_type(4))) unsigned short u16x4;
typedef __attribute__((ext_vector_type(8))) unsigned short u16x8;

__device__ __forceinline__ unsigned short f2b(float f) {
  __hip_bfloat16 h = __float2bfloat16(f);
  return *reinterpret_cast<unsigned short*>(&h);
}

// byte offset in a [64 rows][64 bf16] LDS tile, XOR-swizzled (16B granule)
__device__ __forceinline__ int swz(int row, int kb) {
  return (row * 128 + kb) ^ ((row & 7) << 4);
}
// write target for a k-quad (8B) of row n at k-group kg (kg8 = kg*8 bytes)
__device__ __forceinline__ int swz8(int n, int kg8) {
  return n * 128 + (kg8 ^ ((n & 7) << 4));
}

// ---------------------------------------------------------------- zero
__global__ __launch_bounds__(256) void zero_out_kernel(float* __restrict__ out,
                                                       int* __restrict__ counts) {
  const int n4 = TTOK * HDIM / 4;
  f32x4 z = {0.f, 0.f, 0.f, 0.f};
  for (int i = blockIdx.x * 256 + threadIdx.x; i < n4; i += gridDim.x * 256)
    reinterpret_cast<f32x4*>(out)[i] = z;
  if (blockIdx.x == 0 && threadIdx.x < NEXP) counts[threadIdx.x] = 0;
}

// ---------------------------------------------------------------- gating + x->bf16 (fused)
__global__ __launch_bounds__(256) void gating_kernel(const float* __restrict__ x,
                                                     const float* __restrict__ gw,
                                                     unsigned short* __restrict__ xb,
                                                     float* __restrict__ tw,
                                                     int* __restrict__ counts,
                                                     int* __restrict__ list) {
  const int wv = threadIdx.x >> 6;
  const int lane = threadIdx.x & 63;
  const int t = blockIdx.x * 4 + wv;

  float acc[NEXP];
#pragma unroll
  for (int e = 0; e < NEXP; ++e) acc[e] = 0.f;

  const float* xr = x + (size_t)t * HDIM;
  unsigned short* xbr = xb + (size_t)t * HDIM;
#pragma unroll
  for (int j = 0; j < HDIM / 256; ++j) {
    f32x4 xv = *reinterpret_cast<const f32x4*>(xr + j * 256 + lane * 4);
    u16x4 o;
    o[0] = f2b(xv[0]); o[1] = f2b(xv[1]); o[2] = f2b(xv[2]); o[3] = f2b(xv[3]);
    *reinterpret_cast<u16x4*>(xbr + j * 256 + lane * 4) = o;
#pragma unroll
    for (int e = 0; e < NEXP; ++e) {
      f32x4 gv = *reinterpret_cast<const f32x4*>(gw + (size_t)e * HDIM + j * 256 + lane * 4);
      acc[e] = fmaf(xv[0], gv[0], acc[e]);
      acc[e] = fmaf(xv[1], gv[1], acc[e]);
      acc[e] = fmaf(xv[2], gv[2], acc[e]);
      acc[e] = fmaf(xv[3], gv[3], acc[e]);
    }
  }
#pragma unroll
  for (int e = 0; e < NEXP; ++e) {
#pragma unroll
    for (int off = 32; off; off >>= 1) acc[e] += __shfl_xor(acc[e], off);
  }
  // top-2 (ties -> lowest index, matching lax.top_k)
  int i0 = 0; float s0 = acc[0];
#pragma unroll
  for (int e = 1; e < NEXP; ++e) { if (acc[e] > s0) { s0 = acc[e]; i0 = e; } }
  int i1 = -1; float s1 = -1e30f;
#pragma unroll
  for (int e = 0; e < NEXP; ++e) { if (e != i0 && acc[e] > s1) { s1 = acc[e]; i1 = e; } }

  if (lane == 0) {
    float r = __expf(s1 - s0);          // <= 1
    float w0 = 1.f / (1.f + r);
    float w1 = r / (1.f + r);
    tw[t * 2 + 0] = w0;
    tw[t * 2 + 1] = w1;
    int p0 = atomicAdd(&counts[i0], 1); list[i0 * TTOK + p0] = t * 2 + 0;
    int p1 = atomicAdd(&counts[i1], 1); list[i1 * TTOK + p1] = t * 2 + 1;
  }
}

// ---------------------------------------------------------------- GEMM1
// act[slot, :] = silu(x@wg) * (x@wu) * weight   for each routed slot
__global__ __launch_bounds__(256) void gemm1_kernel(
    const unsigned short* __restrict__ xb, const float* __restrict__ wg,
    const float* __restrict__ wu, const int* __restrict__ counts,
    const int* __restrict__ list, const float* __restrict__ tw,
    unsigned short* __restrict__ act) {
  const int e = blockIdx.z;
  const int cnt = counts[e];
  const int m0 = blockIdx.x * BM;
  if (m0 >= cnt) return;
  const int n0 = blockIdx.y * BN;

  __shared__ __align__(16) char As[BM * BK * 2];   // [m][k], XOR swizzle
  __shared__ __align__(16) char Bgs[BN * BK * 2];  // [n][k], XOR swizzle
  __shared__ __align__(16) char Bus[BN * BK * 2];
  __shared__ int slot_s[BM];
  __shared__ float ws_s[BM];

  const int tid = threadIdx.x;
  if (tid < BM) {
    int mr = m0 + tid;
    int mrc = mr < cnt ? mr : cnt - 1;
    int slot = list[e * TTOK + mrc];
    slot_s[tid] = slot;
    ws_s[tid] = tw[slot];
  }
  __syncthreads();

  // ---- A staging mapping (reg-staged, as in the passing R1) ----
  const int s_row = tid >> 3;   // 0..31 (A-row), second at +32
  const int s_koct = tid & 7;   // k-octet 0..7
  const size_t a_off0 = (size_t)(slot_s[s_row] >> 1) * HDIM;
  const size_t a_off1 = (size_t)(slot_s[s_row + 32] >> 1) * HDIM;

  // ---- B staging mapping: thread owns a 4(k)x4(n) block ----
  const int nq4 = (tid & 15) * 4;         // n columns nq4..nq4+3
  const int kg = tid >> 4;                // k rows kg*4..kg*4+3 (0..15)
  const int kg8 = kg * 8;                 // byte offset of k-quad within row
  const float* bgp = wg + (size_t)e * HDIM * IDIM + (size_t)(kg * 4) * IDIM + n0 + nq4;
  const float* bup = wu + (size_t)e * HDIM * IDIM + (size_t)(kg * 4) * IDIM + n0 + nq4;

  // ---- fragment params ----
  const int lane = tid & 63;
  const int wv = tid >> 6;
  const int wm = (wv >> 1) * 32;
  const int wn = (wv & 1) * 32;
  const int fr = lane & 15;
  const int fk = lane >> 4;

  f32x4 accg[2][2], accu[2][2];
#pragma unroll
  for (int mi = 0; mi < 2; ++mi)
#pragma unroll
    for (int ni = 0; ni < 2; ++ni) {
      accg[mi][ni] = (f32x4){0.f, 0.f, 0.f, 0.f};
      accu[mi][ni] = (f32x4){0.f, 0.f, 0.f, 0.f};
    }

  // prologue: tile 0 into regs
  u16x8 av0 = *reinterpret_cast<const u16x8*>(xb + a_off0 + s_koct * 8);
  u16x8 av1 = *reinterpret_cast<const u16x8*>(xb + a_off1 + s_koct * 8);
  f32x4 rg[4], ru[4];
#pragma unroll
  for (int i = 0; i < 4; ++i) {
    rg[i] = *reinterpret_cast<const f32x4*>(bgp + (size_t)i * IDIM);
    ru[i] = *reinterpret_cast<const f32x4*>(bup + (size_t)i * IDIM);
  }

  for (int k0 = 0; k0 < HDIM; k0 += BK) {
    __syncthreads();   // previous compute done reading LDS
    *reinterpret_cast<u16x8*>(As + swz(s_row, s_koct * 16)) = av0;
    *reinterpret_cast<u16x8*>(As + swz(s_row + 32, s_koct * 16)) = av1;
    // in-thread 4x4 transpose: bf16 quad per column -> [n][k] layout
#pragma unroll
    for (int c = 0; c < 4; ++c) {
      u16x4 tg, tu;
#pragma unroll
      for (int i = 0; i < 4; ++i) { tg[i] = f2b(rg[i][c]); tu[i] = f2b(ru[i][c]); }
      const int wb = swz8(nq4 + c, kg8);
      *reinterpret_cast<u16x4*>(Bgs + wb) = tg;
      *reinterpret_cast<u16x4*>(Bus + wb) = tu;
    }
    __syncthreads();
    // prefetch next tile into regs (overlaps MFMA)
    if (k0 + BK < HDIM) {
      av0 = *reinterpret_cast<const u16x8*>(xb + a_off0 + k0 + BK + s_koct * 8);
      av1 = *reinterpret_cast<const u16x8*>(xb + a_off1 + k0 + BK + s_koct * 8);
#pragma unroll
      for (int i = 0; i < 4; ++i) {
        rg[i] = *reinterpret_cast<const f32x4*>(bgp + (size_t)(k0 + BK + i) * IDIM);
        ru[i] = *reinterpret_cast<const f32x4*>(bup + (size_t)(k0 + BK + i) * IDIM);
      }
    }

#pragma unroll
    for (int ks = 0; ks < 2; ++ks) {
      const int kb = ks * 64 + fk * 16;
      bf16x8 a0 = *reinterpret_cast<const bf16x8*>(As + swz(wm + fr, kb));
      bf16x8 a1 = *reinterpret_cast<const bf16x8*>(As + swz(wm + 16 + fr, kb));
      bf16x8 bg0 = *reinterpret_cast<const bf16x8*>(Bgs + swz(wn + fr, kb));
      bf16x8 bg1 = *reinterpret_cast<const bf16x8*>(Bgs + swz(wn + 16 + fr, kb));
      bf16x8 bu0 = *reinterpret_cast<const bf16x8*>(Bus + swz(wn + fr, kb));
      bf16x8 bu1 = *reinterpret_cast<const bf16x8*>(Bus + swz(wn + 16 + fr, kb));
      accg[0][0] = __builtin_amdgcn_mfma_f32_16x16x32_bf16(a0, bg0, accg[0][0], 0, 0, 0);
      accg[0][1] = __builtin_amdgcn_mfma_f32_16x16x32_bf16(a0, bg1, accg[0][1], 0, 0, 0);
      accg[1][0] = __builtin_amdgcn_mfma_f32_16x16x32_bf16(a1, bg0, accg[1][0], 0, 0, 0);
      accg[1][1] = __builtin_amdgcn_mfma_f32_16x16x32_bf16(a1, bg1, accg[1][1], 0, 0, 0);
      accu[0][0] = __builtin_amdgcn_mfma_f32_16x16x32_bf16(a0, bu0, accu[0][0], 0, 0, 0);
      accu[0][1] = __builtin_amdgcn_mfma_f32_16x16x32_bf16(a0, bu1, accu[0][1], 0, 0, 0);
      accu[1][0] = __builtin_amdgcn_mfma_f32_16x16x32_bf16(a1, bu0, accu[1][0], 0, 0, 0);
      accu[1][1] = __builtin_amdgcn_mfma_f32_16x16x32_bf16(a1, bu1, accu[1][1], 0, 0, 0);
    }
  }

  // epilogue: silu(g)*u*w -> bf16 act
#pragma unroll
  for (int mi = 0; mi < 2; ++mi)
#pragma unroll
    for (int ni = 0; ni < 2; ++ni)
#pragma unroll
      for (int r = 0; r < 4; ++r) {
        const int trow = wm + mi * 16 + fk * 4 + r;
        if (m0 + trow < cnt) {
          const int col = n0 + wn + ni * 16 + fr;
          const float g = accg[mi][ni][r];
          const float u = accu[mi][ni][r];
          const float a = (g / (1.f + __expf(-g))) * u * ws_s[trow];
          act[(size_t)slot_s[trow] * IDIM + col] = f2b(a);
        }
      }
}

// ---------------------------------------------------------------- GEMM2
// out[token, :] += act[slot, :] @ wd[e]
__global__ __launch_bounds__(256) void gemm2_kernel(
    const unsigned short* __restrict__ act, const float* __restrict__ wd,
    const int* __restrict__ counts, const int* __restrict__ list,
    float* __restrict__ out) {
  const int e = blockIdx.z;
  const int cnt = counts[e];
  const int m0 = blockIdx.x * BM;
  if (m0 >= cnt) return;
  const int n0 = blockIdx.y * BN;

  __shared__ __align__(16) char As[BM * BK * 2];
  __shared__ __align__(16) char Bs[BN * BK * 2];
  __shared__ int slot_s[BM];

  const int tid = threadIdx.x;
  if (tid < BM) {
    int mr = m0 + tid;
    int mrc = mr < cnt ? mr : cnt - 1;
    slot_s[tid] = list[e * TTOK + mrc];
  }
  __syncthreads();

  const int s_row = tid >> 3;
  const int s_koct = tid & 7;
  const size_t a_off0 = (size_t)slot_s[s_row] * IDIM;
  const size_t a_off1 = (size_t)slot_s[s_row + 32] * IDIM;

  const int nq4 = (tid & 15) * 4;
  const int kg = tid >> 4;
  const int kg8 = kg * 8;
  const float* bdp = wd + (size_t)e * IDIM * HDIM + (size_t)(kg * 4) * HDIM + n0 + nq4;

  const int lane = tid & 63;
  const int wv = tid >> 6;
  const int wm = (wv >> 1) * 32;
  const int wn = (wv & 1) * 32;
  const int fr = lane & 15;
  const int fk = lane >> 4;

  f32x4 acc[2][2];
#pragma unroll
  for (int mi = 0; mi < 2; ++mi)
#pragma unroll
    for (int ni = 0; ni < 2; ++ni) acc[mi][ni] = (f32x4){0.f, 0.f, 0.f, 0.f};

  u16x8 av0 = *reinterpret_cast<const u16x8*>(act + a_off0 + s_koct * 8);
  u16x8 av1 = *reinterpret_cast<const u16x8*>(act + a_off1 + s_koct * 8);
  f32x4 rb[4];
#pragma unroll
  for (int i = 0; i < 4; ++i)
    rb[i] = *reinterpret_cast<const f32x4*>(bdp + (size_t)i * HDIM);

  for (int k0 = 0; k0 < IDIM; k0 += BK) {
    __syncthreads();
    *reinterpret_cast<u16x8*>(As + swz(s_row, s_koct * 16)) = av0;
    *reinterpret_cast<u16x8*>(As + swz(s_row + 32, s_koct * 16)) = av1;
#pragma unroll
    for (int c = 0; c < 4; ++c) {
      u16x4 tb;
#pragma unroll
      for (int i = 0; i < 4; ++i) tb[i] = f2b(rb[i][c]);
      *reinterpret_cast<u16x4*>(Bs + swz8(nq4 + c, kg8)) = tb;
    }
    __syncthreads();
    if (k0 + BK < IDIM) {
      av0 = *reinterpret_cast<const u16x8*>(act + a_off0 + k0 + BK + s_koct * 8);
      av1 = *reinterpret_cast<const u16x8*>(act + a_off1 + k0 + BK + s_koct * 8);
#pragma unroll
      for (int i = 0; i < 4; ++i)
        rb[i] = *reinterpret_cast<const f32x4*>(bdp + (size_t)(k0 + BK + i) * HDIM);
    }

#pragma unroll
    for (int ks = 0; ks < 2; ++ks) {
      const int kb = ks * 64 + fk * 16;
      bf16x8 a0 = *reinterpret_cast<const bf16x8*>(As + swz(wm + fr, kb));
      bf16x8 a1 = *reinterpret_cast<const bf16x8*>(As + swz(wm + 16 + fr, kb));
      bf16x8 b0 = *reinterpret_cast<const bf16x8*>(Bs + swz(wn + fr, kb));
      bf16x8 b1 = *reinterpret_cast<const bf16x8*>(Bs + swz(wn + 16 + fr, kb));
      acc[0][0] = __builtin_amdgcn_mfma_f32_16x16x32_bf16(a0, b0, acc[0][0], 0, 0, 0);
      acc[0][1] = __builtin_amdgcn_mfma_f32_16x16x32_bf16(a0, b1, acc[0][1], 0, 0, 0);
      acc[1][0] = __builtin_amdgcn_mfma_f32_16x16x32_bf16(a1, b0, acc[1][0], 0, 0, 0);
      acc[1][1] = __builtin_amdgcn_mfma_f32_16x16x32_bf16(a1, b1, acc[1][1], 0, 0, 0);
    }
  }

#pragma unroll
  for (int mi = 0; mi < 2; ++mi)
#pragma unroll
    for (int ni = 0; ni < 2; ++ni)
#pragma unroll
      for (int r = 0; r < 4; ++r) {
        const int trow = wm + mi * 16 + fk * 4 + r;
        if (m0 + trow < cnt) {
          const int t = slot_s[trow] >> 1;
          const int col = n0 + wn + ni * 16 + fr;
          atomicAdd(&out[(size_t)t * HDIM + col], acc[mi][ni][r]);
        }
      }
}

// ---------------------------------------------------------------- launch
extern "C" void kernel_launch(void* const* d_in, const int* in_sizes, int n_in,
                              void* d_out, int out_size, void* d_ws, size_t ws_size,
                              hipStream_t stream) {
  const float* x = (const float*)d_in[0];
  const float* gate_w = (const float*)d_in[1];
  const float* wg = (const float*)d_in[2];
  const float* wu = (const float*)d_in[3];
  const float* wd = (const float*)d_in[4];
  float* out = (float*)d_out;

  char* w = (char*)d_ws;
  size_t off = 0;
  unsigned short* xb = (unsigned short*)(w + off); off += (size_t)TTOK * HDIM * 2;
  unsigned short* act = (unsigned short*)(w + off); off += (size_t)TTOK * KTOP * IDIM * 2;
  float* tw = (float*)(w + off); off += (size_t)TTOK * KTOP * 4;
  int* counts = (int*)(w + off); off += 256;
  int* list = (int*)(w + off); off += (size_t)NEXP * TTOK * 4;

  zero_out_kernel<<<2048, 256, 0, stream>>>(out, counts);
  gating_kernel<<<TTOK / 4, 256, 0, stream>>>(x, gate_w, xb, tw, counts, list);
  gemm1_kernel<<<dim3(TTOK / BM, IDIM / BN, NEXP), 256, 0, stream>>>(
      xb, wg, wu, counts, list, tw, act);
  gemm2_kernel<<<dim3(TTOK / BM, HDIM / BN, NEXP), 256, 0, stream>>>(
      act, wd, counts, list, out);
}

// Round 4
// 512.051 us; speedup vs baseline: 5.8836x; 2.3957x over previous
//
#include <hip/hip_runtime.h>
#include <hip/hip_bf16.h>

#define HDIM 2048
#define IDIM 1024
#define NEXP 16
#define TTOK 4096   // B*S tokens
#define KTOP 2

typedef __attribute__((ext_vector_type(4))) float f32x4;
typedef __attribute__((ext_vector_type(8))) short bf16x8;
typedef __attribute__((ext_vector_type(4))) unsigned short u16x4;
typedef __attribute__((ext_vector_type(8))) unsigned short u16x8;

__device__ __forceinline__ unsigned short f2b(float f) {
  __hip_bfloat16 h = __float2bfloat16(f);
  return *reinterpret_cast<unsigned short*>(&h);
}

// byte offset in a [rows][64 bf16] LDS tile (128 B/row), hash-swizzled.
// slot hash (row ^ (row>>3))&7 spreads BOTH consecutive-row sets (reads,
// A-writes) AND stride-4 row sets (B transpose writes) across all 8
// 16B granules -> uniform bank load (hardware minimum, no conflicts).
__device__ __forceinline__ int swzh(int row, int kb) {
  return row * 128 + (kb ^ (((row ^ (row >> 3)) & 7) << 4));
}

// ---------------------------------------------------------------- zero
__global__ __launch_bounds__(256) void zero_out_kernel(float* __restrict__ out,
                                                       int* __restrict__ counts) {
  const int n4 = TTOK * HDIM / 4;
  f32x4 z = {0.f, 0.f, 0.f, 0.f};
  for (int i = blockIdx.x * 256 + threadIdx.x; i < n4; i += gridDim.x * 256)
    reinterpret_cast<f32x4*>(out)[i] = z;
  if (blockIdx.x == 0 && threadIdx.x < NEXP) counts[threadIdx.x] = 0;
}

// ---------------------------------------------------------------- gating + x->bf16 (fused)
__global__ __launch_bounds__(256) void gating_kernel(const float* __restrict__ x,
                                                     const float* __restrict__ gw,
                                                     unsigned short* __restrict__ xb,
                                                     float* __restrict__ tw,
                                                     int* __restrict__ counts,
                                                     int* __restrict__ list) {
  const int wv = threadIdx.x >> 6;
  const int lane = threadIdx.x & 63;
  const int t = blockIdx.x * 4 + wv;

  float acc[NEXP];
#pragma unroll
  for (int e = 0; e < NEXP; ++e) acc[e] = 0.f;

  const float* xr = x + (size_t)t * HDIM;
  unsigned short* xbr = xb + (size_t)t * HDIM;
#pragma unroll
  for (int j = 0; j < HDIM / 256; ++j) {
    f32x4 xv = *reinterpret_cast<const f32x4*>(xr + j * 256 + lane * 4);
    u16x4 o;
    o[0] = f2b(xv[0]); o[1] = f2b(xv[1]); o[2] = f2b(xv[2]); o[3] = f2b(xv[3]);
    *reinterpret_cast<u16x4*>(xbr + j * 256 + lane * 4) = o;
#pragma unroll
    for (int e = 0; e < NEXP; ++e) {
      f32x4 gv = *reinterpret_cast<const f32x4*>(gw + (size_t)e * HDIM + j * 256 + lane * 4);
      acc[e] = fmaf(xv[0], gv[0], acc[e]);
      acc[e] = fmaf(xv[1], gv[1], acc[e]);
      acc[e] = fmaf(xv[2], gv[2], acc[e]);
      acc[e] = fmaf(xv[3], gv[3], acc[e]);
    }
  }
#pragma unroll
  for (int e = 0; e < NEXP; ++e) {
#pragma unroll
    for (int off = 32; off; off >>= 1) acc[e] += __shfl_xor(acc[e], off);
  }
  // top-2 (ties -> lowest index, matching lax.top_k)
  int i0 = 0; float s0 = acc[0];
#pragma unroll
  for (int e = 1; e < NEXP; ++e) { if (acc[e] > s0) { s0 = acc[e]; i0 = e; } }
  int i1 = -1; float s1 = -1e30f;
#pragma unroll
  for (int e = 0; e < NEXP; ++e) { if (e != i0 && acc[e] > s1) { s1 = acc[e]; i1 = e; } }

  if (lane == 0) {
    float r = __expf(s1 - s0);          // <= 1
    float w0 = 1.f / (1.f + r);
    float w1 = r / (1.f + r);
    tw[t * 2 + 0] = w0;
    tw[t * 2 + 1] = w1;
    int p0 = atomicAdd(&counts[i0], 1); list[i0 * TTOK + p0] = t * 2 + 0;
    int p1 = atomicAdd(&counts[i1], 1); list[i1 * TTOK + p1] = t * 2 + 1;
  }
}

// ---------------------------------------------------------------- GEMM1  (BM=128, BN=64, BK=64)
// act[slot, :] = silu(x@wg) * (x@wu) * weight
// 1D grid, XCD-clustered: e = (bid&7) + 8*((bid>>3)&1); m fastest.
__global__ __launch_bounds__(256) void gemm1_kernel(
    const unsigned short* __restrict__ xb, const float* __restrict__ wg,
    const float* __restrict__ wu, const int* __restrict__ counts,
    const int* __restrict__ list, const float* __restrict__ tw,
    unsigned short* __restrict__ act) {
  const int bid = blockIdx.x;
  const int e = (bid & 7) + 8 * ((bid >> 3) & 1);
  const int mn = bid >> 4;                 // 0..511
  const int mblk = mn & 31;                // m fastest: same-n blocks adjacent
  const int nblk = mn >> 5;                // 0..15
  const int cnt = counts[e];
  const int m0 = mblk * 128;
  if (m0 >= cnt) return;
  const int n0 = nblk * 64;

  __shared__ __align__(16) char As[128 * 128];   // [128 m][64 k] bf16, 16 KB
  __shared__ __align__(16) char Bgs[64 * 128];   // [64 n][64 k] bf16, 8 KB
  __shared__ __align__(16) char Bus[64 * 128];
  __shared__ int slot_s[128];
  __shared__ float ws_s[128];

  const int tid = threadIdx.x;
  if (tid < 128) {
    int mr = m0 + tid;
    int mrc = mr < cnt ? mr : cnt - 1;
    int slot = list[e * TTOK + mrc];
    slot_s[tid] = slot;
    ws_s[tid] = tw[slot];
  }
  __syncthreads();

  // A staging: thread covers rows s_row+32i, k-octet koct
  const int s_row = tid >> 3;              // 0..31
  const int koct = tid & 7;
  const unsigned short* ag[4];
#pragma unroll
  for (int i = 0; i < 4; ++i)
    ag[i] = xb + (size_t)(slot_s[s_row + 32 * i] >> 1) * HDIM + koct * 8;

  // B staging: thread owns 4k x 4n block
  const int nq4 = (tid & 15) * 4;
  const int kg4 = (tid >> 4) * 4;          // k-rows kg4..kg4+3
  const float* bgp = wg + (size_t)e * (HDIM * IDIM) + (size_t)kg4 * IDIM + n0 + nq4;
  const float* bup = wu + (size_t)e * (HDIM * IDIM) + (size_t)kg4 * IDIM + n0 + nq4;

  const int lane = tid & 63;
  const int wv = tid >> 6;
  const int wm = (wv >> 1) * 64;
  const int wn = (wv & 1) * 32;
  const int fr = lane & 15;
  const int fk = lane >> 4;

  f32x4 accg[4][2], accu[4][2];
#pragma unroll
  for (int mi = 0; mi < 4; ++mi)
#pragma unroll
    for (int ni = 0; ni < 2; ++ni) {
      accg[mi][ni] = (f32x4){0.f, 0.f, 0.f, 0.f};
      accu[mi][ni] = (f32x4){0.f, 0.f, 0.f, 0.f};
    }

  // prologue: tile 0 into regs
  u16x8 av[4];
  f32x4 rg[4], ru[4];
#pragma unroll
  for (int i = 0; i < 4; ++i) {
    av[i] = *reinterpret_cast<const u16x8*>(ag[i]);
    rg[i] = *reinterpret_cast<const f32x4*>(bgp + (size_t)i * IDIM);
    ru[i] = *reinterpret_cast<const f32x4*>(bup + (size_t)i * IDIM);
  }

  for (int k0 = 0; k0 < HDIM; k0 += 64) {
    __syncthreads();   // previous compute done reading LDS
#pragma unroll
    for (int i = 0; i < 4; ++i)
      *reinterpret_cast<u16x8*>(As + swzh(s_row + 32 * i, koct * 16)) = av[i];
#pragma unroll
    for (int c = 0; c < 4; ++c) {
      u16x4 tg, tu;
#pragma unroll
      for (int i = 0; i < 4; ++i) { tg[i] = f2b(rg[i][c]); tu[i] = f2b(ru[i][c]); }
      const int wb = swzh(nq4 + c, kg4 * 2);
      *reinterpret_cast<u16x4*>(Bgs + wb) = tg;
      *reinterpret_cast<u16x4*>(Bus + wb) = tu;
    }
    __syncthreads();
    if (k0 + 64 < HDIM) {
#pragma unroll
      for (int i = 0; i < 4; ++i) {
        av[i] = *reinterpret_cast<const u16x8*>(ag[i] + k0 + 64);
        rg[i] = *reinterpret_cast<const f32x4*>(bgp + (size_t)(k0 + 64 + i) * IDIM);
        ru[i] = *reinterpret_cast<const f32x4*>(bup + (size_t)(k0 + 64 + i) * IDIM);
      }
    }

#pragma unroll
    for (int ks = 0; ks < 2; ++ks) {
      const int kb = ks * 64 + fk * 16;
      bf16x8 a[4], bg[2], bu[2];
#pragma unroll
      for (int mi = 0; mi < 4; ++mi)
        a[mi] = *reinterpret_cast<const bf16x8*>(As + swzh(wm + mi * 16 + fr, kb));
#pragma unroll
      for (int ni = 0; ni < 2; ++ni) {
        bg[ni] = *reinterpret_cast<const bf16x8*>(Bgs + swzh(wn + ni * 16 + fr, kb));
        bu[ni] = *reinterpret_cast<const bf16x8*>(Bus + swzh(wn + ni * 16 + fr, kb));
      }
#pragma unroll
      for (int mi = 0; mi < 4; ++mi)
#pragma unroll
        for (int ni = 0; ni < 2; ++ni) {
          accg[mi][ni] = __builtin_amdgcn_mfma_f32_16x16x32_bf16(a[mi], bg[ni], accg[mi][ni], 0, 0, 0);
          accu[mi][ni] = __builtin_amdgcn_mfma_f32_16x16x32_bf16(a[mi], bu[ni], accu[mi][ni], 0, 0, 0);
        }
    }
  }

  // epilogue: silu(g)*u*w -> bf16 act
#pragma unroll
  for (int mi = 0; mi < 4; ++mi)
#pragma unroll
    for (int ni = 0; ni < 2; ++ni)
#pragma unroll
      for (int r = 0; r < 4; ++r) {
        const int trow = wm + mi * 16 + fk * 4 + r;
        if (m0 + trow < cnt) {
          const int col = n0 + wn + ni * 16 + fr;
          const float g = accg[mi][ni][r];
          const float u = accu[mi][ni][r];
          const float a = (g / (1.f + __expf(-g))) * u * ws_s[trow];
          act[(size_t)slot_s[trow] * IDIM + col] = f2b(a);
        }
      }
}

// ---------------------------------------------------------------- GEMM2  (BM=128, BN=128, BK=64)
// out[token, :] += act[slot, :] @ wd[e]
__global__ __launch_bounds__(256) void gemm2_kernel(
    const unsigned short* __restrict__ act, const float* __restrict__ wd,
    const int* __restrict__ counts, const int* __restrict__ list,
    float* __restrict__ out) {
  const int bid = blockIdx.x;
  const int e = (bid & 7) + 8 * ((bid >> 3) & 1);
  const int mn = bid >> 4;                 // 0..511
  const int mblk = mn & 31;
  const int nblk = mn >> 5;                // 0..15
  const int cnt = counts[e];
  const int m0 = mblk * 128;
  if (m0 >= cnt) return;
  const int n0 = nblk * 128;

  __shared__ __align__(16) char As[128 * 128];   // [128 m][64 k] bf16
  __shared__ __align__(16) char Bs[128 * 128];   // [128 n][64 k] bf16
  __shared__ int slot_s[128];

  const int tid = threadIdx.x;
  if (tid < 128) {
    int mr = m0 + tid;
    int mrc = mr < cnt ? mr : cnt - 1;
    slot_s[tid] = list[e * TTOK + mrc];
  }
  __syncthreads();

  const int s_row = tid >> 3;
  const int koct = tid & 7;
  const unsigned short* ag[4];
#pragma unroll
  for (int i = 0; i < 4; ++i)
    ag[i] = act + (size_t)slot_s[s_row + 32 * i] * IDIM + koct * 8;

  const int nq4 = (tid & 15) * 4;
  const int kg4 = (tid >> 4) * 4;
  const float* bdp = wd + (size_t)e * (IDIM * HDIM) + (size_t)kg4 * HDIM + n0 + nq4;

  const int lane = tid & 63;
  const int wv = tid >> 6;
  const int wm = (wv >> 1) * 64;
  const int wn = (wv & 1) * 64;
  const int fr = lane & 15;
  const int fk = lane >> 4;

  f32x4 acc[4][4];
#pragma unroll
  for (int mi = 0; mi < 4; ++mi)
#pragma unroll
    for (int ni = 0; ni < 4; ++ni) acc[mi][ni] = (f32x4){0.f, 0.f, 0.f, 0.f};

  u16x8 av[4];
  f32x4 rb0[4], rb1[4];
#pragma unroll
  for (int i = 0; i < 4; ++i) {
    av[i] = *reinterpret_cast<const u16x8*>(ag[i]);
    rb0[i] = *reinterpret_cast<const f32x4*>(bdp + (size_t)i * HDIM);
    rb1[i] = *reinterpret_cast<const f32x4*>(bdp + (size_t)i * HDIM + 64);
  }

  for (int k0 = 0; k0 < IDIM; k0 += 64) {
    __syncthreads();
#pragma unroll
    for (int i = 0; i < 4; ++i)
      *reinterpret_cast<u16x8*>(As + swzh(s_row + 32 * i, koct * 16)) = av[i];
#pragma unroll
    for (int c = 0; c < 4; ++c) {
      u16x4 t0, t1;
#pragma unroll
      for (int i = 0; i < 4; ++i) { t0[i] = f2b(rb0[i][c]); t1[i] = f2b(rb1[i][c]); }
      *reinterpret_cast<u16x4*>(Bs + swzh(nq4 + c, kg4 * 2)) = t0;
      *reinterpret_cast<u16x4*>(Bs + swzh(64 + nq4 + c, kg4 * 2)) = t1;
    }
    __syncthreads();
    if (k0 + 64 < IDIM) {
#pragma unroll
      for (int i = 0; i < 4; ++i) {
        av[i] = *reinterpret_cast<const u16x8*>(ag[i] + k0 + 64);
        rb0[i] = *reinterpret_cast<const f32x4*>(bdp + (size_t)(k0 + 64 + i) * HDIM);
        rb1[i] = *reinterpret_cast<const f32x4*>(bdp + (size_t)(k0 + 64 + i) * HDIM + 64);
      }
    }

#pragma unroll
    for (int ks = 0; ks < 2; ++ks) {
      const int kb = ks * 64 + fk * 16;
      bf16x8 a[4], b[4];
#pragma unroll
      for (int mi = 0; mi < 4; ++mi)
        a[mi] = *reinterpret_cast<const bf16x8*>(As + swzh(wm + mi * 16 + fr, kb));
#pragma unroll
      for (int ni = 0; ni < 4; ++ni)
        b[ni] = *reinterpret_cast<const bf16x8*>(Bs + swzh(wn + ni * 16 + fr, kb));
#pragma unroll
      for (int mi = 0; mi < 4; ++mi)
#pragma unroll
        for (int ni = 0; ni < 4; ++ni)
          acc[mi][ni] = __builtin_amdgcn_mfma_f32_16x16x32_bf16(a[mi], b[ni], acc[mi][ni], 0, 0, 0);
    }
  }

#pragma unroll
  for (int mi = 0; mi < 4; ++mi)
#pragma unroll
    for (int ni = 0; ni < 4; ++ni)
#pragma unroll
      for (int r = 0; r < 4; ++r) {
        const int trow = wm + mi * 16 + fk * 4 + r;
        if (m0 + trow < cnt) {
          const int t = slot_s[trow] >> 1;
          const int col = n0 + wn + ni * 16 + fr;
          atomicAdd(&out[(size_t)t * HDIM + col], acc[mi][ni][r]);
        }
      }
}

// ---------------------------------------------------------------- launch
extern "C" void kernel_launch(void* const* d_in, const int* in_sizes, int n_in,
                              void* d_out, int out_size, void* d_ws, size_t ws_size,
                              hipStream_t stream) {
  const float* x = (const float*)d_in[0];
  const float* gate_w = (const float*)d_in[1];
  const float* wg = (const float*)d_in[2];
  const float* wu = (const float*)d_in[3];
  const float* wd = (const float*)d_in[4];
  float* out = (float*)d_out;

  char* w = (char*)d_ws;
  size_t off = 0;
  unsigned short* xb = (unsigned short*)(w + off); off += (size_t)TTOK * HDIM * 2;
  unsigned short* act = (unsigned short*)(w + off); off += (size_t)TTOK * KTOP * IDIM * 2;
  float* tw = (float*)(w + off); off += (size_t)TTOK * KTOP * 4;
  int* counts = (int*)(w + off); off += 256;
  int* list = (int*)(w + off); off += (size_t)NEXP * TTOK * 4;

  zero_out_kernel<<<2048, 256, 0, stream>>>(out, counts);
  gating_kernel<<<TTOK / 4, 256, 0, stream>>>(x, gate_w, xb, tw, counts, list);
  // gemm1: 16 e x 32 m x 16 n = 8192 blocks (XCD-clustered decode in-kernel)
  gemm1_kernel<<<8192, 256, 0, stream>>>(xb, wg, wu, counts, list, tw, act);
  // gemm2: 16 e x 32 m x 16 n = 8192 blocks
  gemm2_kernel<<<8192, 256, 0, stream>>>(act, wd, counts, list, out);
}